// Round 19
// baseline (91.907 us; speedup 1.0000x reference)
//
#include <hip/hip_runtime.h>
#include <hip/hip_bf16.h>
#include <stdint.h>

// SymmetricTensorProduct: n=8192, MUL=128, DIM_IN=512
//   out_s[z,u] = (1/16)*xs[z,u]*S[z,u] + (1/(16*sqrt3))*sum_i V_i[z,u]*xv[z,u,i]
//   t[z,v,w]   = sum_u xs[z,u]*w_sv[u,v,w]
//   out_v[z,w,i] = (1/128)*sum_v t[z,v,w]*xv[z,v,i]
//
// Round-19: outv = r13's exact depth-2 wave body in 256-THREAD blocks
// (4 waves = 2 wg x 2 vg; zg axis moved to grid). Grid 1024 = 256 zb(32z)
// x 4 wc(32w). LDS 12.8KB/block, __launch_bounds__(256,4) -> VGPR cap 64
// (r13's body verified to fit). Tests the block-packing hypothesis: 512-thr
// blocks never exceeded 37% occupancy across r8/r13/r15; smaller blocks
// pack finer (4 blocks/CU, 4-wave barriers) at identical wave count.
// prep_all unchanged from r18 (merged x-transpose + Wt reorder + out_s).

#define NZ 8192
#define SLAB 548864   // ushorts per wc slab (134 tiles; 128 used + 6 pad)

typedef __attribute__((ext_vector_type(8))) short bf16x8;
typedef __attribute__((ext_vector_type(4))) float f32x4;

__device__ __forceinline__ ushort f2bf(float f) {
  uint32_t u = __builtin_bit_cast(uint32_t, f);
  u += 0x7fffu + ((u >> 16) & 1u);   // RNE
  return (ushort)(u >> 16);
}
__device__ __forceinline__ float bf2f(ushort u) {
  uint32_t v = ((uint32_t)u) << 16;
  return __builtin_bit_cast(float, v);
}

// -------- prep_all: x transpose (256) + Wt reorder (512) + out_s (512) ------
__global__ __launch_bounds__(256) void prep_all(
    const float* __restrict__ x, const float* __restrict__ w_ss,
    const float* __restrict__ w_vv, const float* __restrict__ w_sv,
    ushort* __restrict__ xs_bf, ushort* __restrict__ xvt,
    ushort* __restrict__ Wt, float* __restrict__ out) {
  __shared__ ushort tile[12288];
  int bid = blockIdx.x, tid = threadIdx.x;
  if (bid < 256) {
    // x -> xs_bf[z][u] and xvt[i][v][z] (LDS transpose), 32 z per block
    int z0 = bid * 32;
#pragma unroll
    for (int it = 0; it < 16; ++it) {
      int idx = it * 256 + tid;             // 0..4095
      int zloc = idx >> 7, c4 = idx & 127;
      float4 f = *(const float4*)(x + (size_t)(z0 + zloc) * 512 + c4 * 4);
      if (c4 < 32) {
        ushort4 o;
        o.x = f2bf(f.x); o.y = f2bf(f.y); o.z = f2bf(f.z); o.w = f2bf(f.w);
        *(ushort4*)(xs_bf + (size_t)(z0 + zloc) * 128 + c4 * 4) = o;
      } else {
        int c = c4 * 4 - 128;               // 0..383
        float vals[4] = {f.x, f.y, f.z, f.w};
#pragma unroll
        for (int e = 0; e < 4; ++e) {
          int cc = c + e, v = cc / 3, i = cc - 3 * v;
          tile[i * 4096 + v * 32 + zloc] = f2bf(vals[e]);
        }
      }
    }
    __syncthreads();
#pragma unroll
    for (int it = 0; it < 6; ++it) {
      int j = it * 256 + tid;               // 0..1535 vec8s
      int row = j >> 2, part = j & 3;       // row: i*128+v
      int i = row >> 7, v = row & 127;
      *(bf16x8*)(xvt + ((size_t)i * 128 + v) * 8192 + z0 + part * 8) =
          *(const bf16x8*)(tile + i * 4096 + v * 32 + part * 8);
    }
  } else if (bid < 768) {
    // w_sv[u][v][w] -> Wt [wc][v][wg][kk][l][e] fragment order
    int q = bid - 256;
    int v = q >> 2, wc = q & 3;
    int u = tid >> 1, wh = tid & 1;
    const float* src = w_sv + (size_t)u * 16384 + v * 128 + wc * 32 + wh * 16;
    int kk = u >> 5, lg = (u >> 3) & 3, e = u & 7;
#pragma unroll
    for (int ww = 0; ww < 16; ++ww)
      tile[wh * 2048 + kk * 512 + (lg * 16 + ww) * 8 + e] = f2bf(src[ww]);
    __syncthreads();
    bf16x8* dst = (bf16x8*)(Wt + (size_t)wc * SLAB + (size_t)v * 4096);
    const bf16x8* s = (const bf16x8*)tile;
    dst[tid] = s[tid];
    dst[tid + 256] = s[tid + 256];
  } else {
    // out_s via MFMA; self-casts xs and w rows from fp32 (no prep dependency)
    int q = bid - 768;                      // 0..511 = 128 zb x 4 uh
    int uh = q & 3, zb = q >> 2;
    int wid = tid >> 6, l = tid & 63;
    int lr = l & 15, lg = l >> 4;
    int z = zb * 64 + wid * 16 + lr;
    const float* xrow = x + (size_t)z * 512;

    bf16x8 bs[4], b0[4], b1[4], b2[4];
#pragma unroll
    for (int kk = 0; kk < 4; ++kk) {
      int k0 = kk * 32 + lg * 8;
      {
        float4 g0 = *(const float4*)(xrow + k0);
        float4 g1 = *(const float4*)(xrow + k0 + 4);
        const float* gg = (const float*)&g0;
        const float* hh = (const float*)&g1;
#pragma unroll
        for (int jj = 0; jj < 4; ++jj) {
          bs[kk][jj] = (short)f2bf(gg[jj]);
          bs[kk][jj + 4] = (short)f2bf(hh[jj]);
        }
      }
      float4 f[6];
      const float4* src = (const float4*)(xrow + 128 + 3 * k0);
#pragma unroll
      for (int p = 0; p < 6; ++p) f[p] = src[p];
      const float* ff = (const float*)f;
#pragma unroll
      for (int jj = 0; jj < 8; ++jj) {
        b0[kk][jj] = (short)f2bf(ff[3 * jj + 0]);
        b1[kk][jj] = (short)f2bf(ff[3 * jj + 1]);
        b2[kk][jj] = (short)f2bf(ff[3 * jj + 2]);
      }
    }
#pragma unroll
    for (int uu = 0; uu < 2; ++uu) {
      int u0 = (uh * 2 + uu) * 16;
      f32x4 css = {0.f, 0.f, 0.f, 0.f};
      f32x4 cv0 = {0.f, 0.f, 0.f, 0.f};
      f32x4 cv1 = {0.f, 0.f, 0.f, 0.f};
      f32x4 cv2 = {0.f, 0.f, 0.f, 0.f};
#pragma unroll
      for (int kk = 0; kk < 4; ++kk) {
        int k0 = kk * 32 + lg * 8;
        const float* wsr = w_ss + (size_t)(u0 + lr) * 128 + k0;
        const float* wvr = w_vv + (size_t)(u0 + lr) * 128 + k0;
        float4 s0 = *(const float4*)(wsr), s1 = *(const float4*)(wsr + 4);
        float4 v0 = *(const float4*)(wvr), v1 = *(const float4*)(wvr + 4);
        bf16x8 as, av;
        const float* sp0 = (const float*)&s0;
        const float* sp1 = (const float*)&s1;
        const float* vp0 = (const float*)&v0;
        const float* vp1 = (const float*)&v1;
#pragma unroll
        for (int jj = 0; jj < 4; ++jj) {
          as[jj] = (short)f2bf(sp0[jj]); as[jj + 4] = (short)f2bf(sp1[jj]);
          av[jj] = (short)f2bf(vp0[jj]); av[jj + 4] = (short)f2bf(vp1[jj]);
        }
        css = __builtin_amdgcn_mfma_f32_16x16x32_bf16(as, bs[kk], css, 0, 0, 0);
        cv0 = __builtin_amdgcn_mfma_f32_16x16x32_bf16(av, b0[kk], cv0, 0, 0, 0);
        cv1 = __builtin_amdgcn_mfma_f32_16x16x32_bf16(av, b1[kk], cv1, 0, 0, 0);
        cv2 = __builtin_amdgcn_mfma_f32_16x16x32_bf16(av, b2[kk], cv2, 0, 0, 0);
      }
#pragma unroll
      for (int r = 0; r < 4; ++r) {
        int u = u0 + lg * 4 + r;
        float xsv = xrow[u];
        const float* xvu = xrow + 128 + 3 * u;
        out[(size_t)z * 512 + u] =
            0.0625f * xsv * css[r] +
            0.036084391824351615f * (cv0[r] * xvu[0] + cv1[r] * xvu[1] + cv2[r] * xvu[2]);
      }
    }
  }
}

// ---------------- out_v: barrier-free global stream, 256-thr blocks ---------
#define LOADV(V_, PA, XA)                                                      \
  do {                                                                         \
    const ushort* ap = Ap + (size_t)(V_) * 4096;                               \
    PA[0] = *(const bf16x8*)(ap);                                              \
    PA[1] = *(const bf16x8*)(ap + 512);                                        \
    PA[2] = *(const bf16x8*)(ap + 1024);                                       \
    PA[3] = *(const bf16x8*)(ap + 1536);                                       \
    XA[0] = xq0[(size_t)(V_) * 8192];                                          \
    XA[1] = xq0[(size_t)(V_) * 8192 + 16];                                     \
    XA[2] = xq1[(size_t)(V_) * 8192];                                          \
    XA[3] = xq1[(size_t)(V_) * 8192 + 16];                                     \
    XA[4] = xq2[(size_t)(V_) * 8192];                                          \
    XA[5] = xq2[(size_t)(V_) * 8192 + 16];                                     \
  } while (0)

#define COMPUTEV(PA, XA)                                                       \
  do {                                                                         \
    _Pragma("unroll")                                                          \
    for (int n = 0; n < 2; ++n) {                                              \
      f32x4 tt = {0.f, 0.f, 0.f, 0.f};                                         \
      __builtin_amdgcn_s_setprio(1);                                           \
      tt = __builtin_amdgcn_mfma_f32_16x16x32_bf16(PA[0], b[n][0], tt, 0, 0, 0);\
      tt = __builtin_amdgcn_mfma_f32_16x16x32_bf16(PA[1], b[n][1], tt, 0, 0, 0);\
      tt = __builtin_amdgcn_mfma_f32_16x16x32_bf16(PA[2], b[n][2], tt, 0, 0, 0);\
      tt = __builtin_amdgcn_mfma_f32_16x16x32_bf16(PA[3], b[n][3], tt, 0, 0, 0);\
      __builtin_amdgcn_s_setprio(0);                                           \
      float x0 = bf2f(XA[0 + n]);                                              \
      float x1 = bf2f(XA[2 + n]);                                              \
      float x2 = bf2f(XA[4 + n]);                                              \
      _Pragma("unroll")                                                        \
      for (int r = 0; r < 4; ++r) {                                            \
        acc[n][r][0] += tt[r] * x0;                                            \
        acc[n][r][1] += tt[r] * x1;                                            \
        acc[n][r][2] += tt[r] * x2;                                            \
      }                                                                        \
    }                                                                          \
  } while (0)

__global__ __launch_bounds__(256, 4) void outv_kernel(
    const ushort* __restrict__ xs_bf, const ushort* __restrict__ xvt,
    const ushort* __restrict__ Wt, float* __restrict__ out) {
  __shared__ float red[128][25];     // 12.8KB, epilogue only
  int bid = blockIdx.x;
  int wc = bid & 3, zb = bid >> 2;   // zb 0..255, 32 z each
  int tid = threadIdx.x;
  int wid = tid >> 6, l = tid & 63;
  int vg = wid & 1, wg = wid >> 1;   // 4 waves = 2 vg x 2 wg
  int lr = l & 15, lg = l >> 4;
  int zbase = zb * 32 + lr;          // n-tile adds 16
  int w0 = wc * 32 + wg * 16;
  int vbase = vg * 64;

  // per-wave A stream base: fragment-order tile [wg][kk][l][e]
  const ushort* Ap = Wt + (size_t)wc * SLAB + (size_t)vbase * 4096 + wg * 2048 + l * 8;
  const ushort* xq0 = xvt + ((size_t)(0 * 128 + vbase)) * 8192 + zbase;
  const ushort* xq1 = xvt + ((size_t)(1 * 128 + vbase)) * 8192 + zbase;
  const ushort* xq2 = xvt + ((size_t)(2 * 128 + vbase)) * 8192 + zbase;

  // B-fragments (xs): 2 n-tiles x 4 k-chunks, held all kernel
  bf16x8 b[2][4];
#pragma unroll
  for (int n = 0; n < 2; ++n)
#pragma unroll
    for (int kk = 0; kk < 4; ++kk)
      b[n][kk] = *(const bf16x8*)(xs_bf + (size_t)(zbase + n * 16) * 128 + kk * 32 + lg * 8);

  float acc[2][4][3] = {};
  bf16x8 pa[4], pb[4];
  ushort xa[6], xb[6];

  LOADV(0, pa, xa);
  __builtin_amdgcn_sched_barrier(0);

  for (int q = 0; q < 32; ++q) {
    LOADV(2 * q + 1, pb, xb);
    __builtin_amdgcn_sched_barrier(0);
    COMPUTEV(pa, xa);
    __builtin_amdgcn_sched_barrier(0);
    LOADV(2 * q + 2, pa, xa);      // q=31 reads tile vbase+64 (pad for vg=1;
    __builtin_amdgcn_sched_barrier(0);  // vg=0 reads vg=1's tile 64; discarded)
    COMPUTEV(pb, xb);
    __builtin_amdgcn_sched_barrier(0);
  }

  // vg combine: vg1 -> LDS, vg0 adds + stores
  int rrow = wg * 64 + l;
  if (vg == 1) {
#pragma unroll
    for (int n = 0; n < 2; ++n)
#pragma unroll
      for (int r = 0; r < 4; ++r)
#pragma unroll
        for (int i = 0; i < 3; ++i)
          red[rrow][(n * 4 + r) * 3 + i] = acc[n][r][i];
  }
  __syncthreads();
  if (vg == 0) {
#pragma unroll
    for (int n = 0; n < 2; ++n) {
#pragma unroll
      for (int r = 0; r < 4; ++r) {
        int z = zbase + n * 16;
        int w = w0 + lg * 4 + r;
        float* o = out + (size_t)z * 512 + 128 + 3 * w;
        o[0] = (acc[n][r][0] + red[rrow][(n * 4 + r) * 3 + 0]) * 0.0078125f;
        o[1] = (acc[n][r][1] + red[rrow][(n * 4 + r) * 3 + 1]) * 0.0078125f;
        o[2] = (acc[n][r][2] + red[rrow][(n * 4 + r) * 3 + 2]) * 0.0078125f;
      }
    }
  }
}

// ---------------- launch ----------------------------------------------------
extern "C" void kernel_launch(void* const* d_in, const int* in_sizes, int n_in,
                              void* d_out, int out_size, void* d_ws, size_t ws_size,
                              hipStream_t stream) {
  const float* x    = (const float*)d_in[0];
  const float* w_ss = (const float*)d_in[1];
  const float* w_sv = (const float*)d_in[2];
  const float* w_vv = (const float*)d_in[3];
  float* out = (float*)d_out;

  char* ws = (char*)d_ws;
  ushort* xs_bf = (ushort*)ws;                                  // 2 MB
  ushort* Wt    = (ushort*)(ws + (size_t)2 * 1024 * 1024);      // 4.39 MB used
  ushort* xvt   = (ushort*)(ws + (size_t)6656 * 1024);          // 6 MB @ 6.5MB

  prep_all<<<1280, 256, 0, stream>>>(x, w_ss, w_vv, w_sv, xs_bf, xvt, Wt, out);
  outv_kernel<<<1024, 256, 0, stream>>>(xs_bf, xvt, Wt, out);
}

// Round 20
// 82.280 us; speedup vs baseline: 1.1170x; 1.1170x over previous
//
#include <hip/hip_runtime.h>
#include <hip/hip_bf16.h>
#include <stdint.h>

// SymmetricTensorProduct: n=8192, MUL=128, DIM_IN=512
//   out_s[z,u] = (1/16)*xs[z,u]*S[z,u] + (1/(16*sqrt3))*sum_i V_i[z,u]*xv[z,u,i]
//   t[z,v,w]   = sum_u xs[z,u]*w_sv[u,v,w]
//   out_v[z,w,i] = (1/128)*sum_v t[z,v,w]*xv[z,v,i]
//
// Round-20: outv LOCKED at r18 (best verified: outv 64.6us, VGPR 96, no
// spill; 5 structural alternatives all slower). prep_all's Wt branch
// rewritten for coalesced w_sv reads: 128 one-per-v blocks read rows
// w_sv[u][v][0:128] coalesced -> LDS bf16 [u][w] (32KB) -> fragment-order
// coalesced vec8 writes. Eliminates the scattered-64B 2x overfetch on the
// 64MB w_sv stream. Transpose + outs branches unchanged.

#define NZ 8192
#define SLAB 548864   // ushorts per wc slab (134 tiles; 128 used + 6 pad)

typedef __attribute__((ext_vector_type(8))) short bf16x8;
typedef __attribute__((ext_vector_type(4))) float f32x4;

__device__ __forceinline__ ushort f2bf(float f) {
  uint32_t u = __builtin_bit_cast(uint32_t, f);
  u += 0x7fffu + ((u >> 16) & 1u);   // RNE
  return (ushort)(u >> 16);
}
__device__ __forceinline__ float bf2f(ushort u) {
  uint32_t v = ((uint32_t)u) << 16;
  return __builtin_bit_cast(float, v);
}

// -- prep_all: x transpose (256) + Wt reorder (128, coalesced) + out_s (512) -
__global__ __launch_bounds__(256) void prep_all(
    const float* __restrict__ x, const float* __restrict__ w_ss,
    const float* __restrict__ w_vv, const float* __restrict__ w_sv,
    ushort* __restrict__ xs_bf, ushort* __restrict__ xvt,
    ushort* __restrict__ Wt, float* __restrict__ out) {
  __shared__ ushort tile[16384];   // 32KB: transpose uses 12288, Wt uses 16384
  int bid = blockIdx.x, tid = threadIdx.x;
  if (bid < 256) {
    // x -> xs_bf[z][u] and xvt[i][v][z] (LDS transpose), 32 z per block
    int z0 = bid * 32;
#pragma unroll
    for (int it = 0; it < 16; ++it) {
      int idx = it * 256 + tid;             // 0..4095
      int zloc = idx >> 7, c4 = idx & 127;
      float4 f = *(const float4*)(x + (size_t)(z0 + zloc) * 512 + c4 * 4);
      if (c4 < 32) {
        ushort4 o;
        o.x = f2bf(f.x); o.y = f2bf(f.y); o.z = f2bf(f.z); o.w = f2bf(f.w);
        *(ushort4*)(xs_bf + (size_t)(z0 + zloc) * 128 + c4 * 4) = o;
      } else {
        int c = c4 * 4 - 128;               // 0..383
        float vals[4] = {f.x, f.y, f.z, f.w};
#pragma unroll
        for (int e = 0; e < 4; ++e) {
          int cc = c + e, v = cc / 3, i = cc - 3 * v;
          tile[i * 4096 + v * 32 + zloc] = f2bf(vals[e]);
        }
      }
    }
    __syncthreads();
#pragma unroll
    for (int it = 0; it < 6; ++it) {
      int j = it * 256 + tid;               // 0..1535 vec8s
      int row = j >> 2, part = j & 3;       // row: i*128+v
      int i = row >> 7, v = row & 127;
      *(bf16x8*)(xvt + ((size_t)i * 128 + v) * 8192 + z0 + part * 8) =
          *(const bf16x8*)(tile + i * 4096 + v * 32 + part * 8);
    }
  } else if (bid < 384) {
    // w_sv[u][v][w] -> Wt [wc][v][wg][kk][l][e]; coalesced row reads.
    int v = bid - 256;
    // stage: LDS bf16 tile [u][w] 128x128 (32KB); lanes read consecutive
    // float4 within a 512B row -> fully coalesced.
#pragma unroll
    for (int it = 0; it < 16; ++it) {
      int u = (tid >> 5) + 8 * it;
      int w4 = (tid & 31) * 4;
      float4 f = *(const float4*)(w_sv + (size_t)u * 16384 + (size_t)v * 128 + w4);
      ushort4 o;
      o.x = f2bf(f.x); o.y = f2bf(f.y); o.z = f2bf(f.z); o.w = f2bf(f.w);
      *(ushort4*)(tile + u * 128 + w4) = o;
    }
    __syncthreads();
    // emit 4 wc fragment-order tiles; thread t writes 16 consecutive ushorts
    // per wc (2 coalesced vec8 stores). o = wg*2048+kk*512+(lg*16+lw)*8+e.
#pragma unroll
    for (int wc = 0; wc < 4; ++wc) {
      bf16x8 v0, v1;
#pragma unroll
      for (int j = 0; j < 16; ++j) {
        int o = tid * 16 + j;
        int wg = o >> 11;
        int kk = (o >> 9) & 3;
        int lglw = (o >> 3) & 63;
        int lg = lglw >> 4, lw = lglw & 15;
        int e = o & 7;
        int u = kk * 32 + lg * 8 + e;
        int w = wc * 32 + wg * 16 + lw;
        ushort val = tile[u * 128 + w];
        if (j < 8) v0[j] = (short)val; else v1[j - 8] = (short)val;
      }
      ushort* dst = Wt + (size_t)wc * SLAB + (size_t)v * 4096 + tid * 16;
      *(bf16x8*)(dst) = v0;
      *(bf16x8*)(dst + 8) = v1;
    }
  } else {
    // out_s via MFMA; self-casts xs and w rows from fp32 (no prep dependency)
    int q = bid - 384;                      // 0..511 = 128 zb x 4 uh
    int uh = q & 3, zb = q >> 2;
    int wid = tid >> 6, l = tid & 63;
    int lr = l & 15, lg = l >> 4;
    int z = zb * 64 + wid * 16 + lr;
    const float* xrow = x + (size_t)z * 512;

    bf16x8 bs[4], b0[4], b1[4], b2[4];
#pragma unroll
    for (int kk = 0; kk < 4; ++kk) {
      int k0 = kk * 32 + lg * 8;
      {
        float4 g0 = *(const float4*)(xrow + k0);
        float4 g1 = *(const float4*)(xrow + k0 + 4);
        const float* gg = (const float*)&g0;
        const float* hh = (const float*)&g1;
#pragma unroll
        for (int jj = 0; jj < 4; ++jj) {
          bs[kk][jj] = (short)f2bf(gg[jj]);
          bs[kk][jj + 4] = (short)f2bf(hh[jj]);
        }
      }
      float4 f[6];
      const float4* src = (const float4*)(xrow + 128 + 3 * k0);
#pragma unroll
      for (int p = 0; p < 6; ++p) f[p] = src[p];
      const float* ff = (const float*)f;
#pragma unroll
      for (int jj = 0; jj < 8; ++jj) {
        b0[kk][jj] = (short)f2bf(ff[3 * jj + 0]);
        b1[kk][jj] = (short)f2bf(ff[3 * jj + 1]);
        b2[kk][jj] = (short)f2bf(ff[3 * jj + 2]);
      }
    }
#pragma unroll
    for (int uu = 0; uu < 2; ++uu) {
      int u0 = (uh * 2 + uu) * 16;
      f32x4 css = {0.f, 0.f, 0.f, 0.f};
      f32x4 cv0 = {0.f, 0.f, 0.f, 0.f};
      f32x4 cv1 = {0.f, 0.f, 0.f, 0.f};
      f32x4 cv2 = {0.f, 0.f, 0.f, 0.f};
#pragma unroll
      for (int kk = 0; kk < 4; ++kk) {
        int k0 = kk * 32 + lg * 8;
        const float* wsr = w_ss + (size_t)(u0 + lr) * 128 + k0;
        const float* wvr = w_vv + (size_t)(u0 + lr) * 128 + k0;
        float4 s0 = *(const float4*)(wsr), s1 = *(const float4*)(wsr + 4);
        float4 v0 = *(const float4*)(wvr), v1 = *(const float4*)(wvr + 4);
        bf16x8 as, av;
        const float* sp0 = (const float*)&s0;
        const float* sp1 = (const float*)&s1;
        const float* vp0 = (const float*)&v0;
        const float* vp1 = (const float*)&v1;
#pragma unroll
        for (int jj = 0; jj < 4; ++jj) {
          as[jj] = (short)f2bf(sp0[jj]); as[jj + 4] = (short)f2bf(sp1[jj]);
          av[jj] = (short)f2bf(vp0[jj]); av[jj + 4] = (short)f2bf(vp1[jj]);
        }
        css = __builtin_amdgcn_mfma_f32_16x16x32_bf16(as, bs[kk], css, 0, 0, 0);
        cv0 = __builtin_amdgcn_mfma_f32_16x16x32_bf16(av, b0[kk], cv0, 0, 0, 0);
        cv1 = __builtin_amdgcn_mfma_f32_16x16x32_bf16(av, b1[kk], cv1, 0, 0, 0);
        cv2 = __builtin_amdgcn_mfma_f32_16x16x32_bf16(av, b2[kk], cv2, 0, 0, 0);
      }
#pragma unroll
      for (int r = 0; r < 4; ++r) {
        int u = u0 + lg * 4 + r;
        float xsv = xrow[u];
        const float* xvu = xrow + 128 + 3 * u;
        out[(size_t)z * 512 + u] =
            0.0625f * xsv * css[r] +
            0.036084391824351615f * (cv0[r] * xvu[0] + cv1[r] * xvu[1] + cv2[r] * xvu[2]);
      }
    }
  }
}

// ---------------- out_v: barrier-free global stream, depth-3 pipeline -------
#define LOADV(V_, PA, XA)                                                      \
  do {                                                                         \
    int vc_ = (V_) > 63 ? 63 : (V_);                                           \
    const ushort* ap = Ap + (size_t)vc_ * 4096;                                \
    PA[0] = *(const bf16x8*)(ap);                                              \
    PA[1] = *(const bf16x8*)(ap + 512);                                        \
    PA[2] = *(const bf16x8*)(ap + 1024);                                       \
    PA[3] = *(const bf16x8*)(ap + 1536);                                       \
    XA[0] = xq0[(size_t)vc_ * 8192];                                           \
    XA[1] = xq0[(size_t)vc_ * 8192 + 16];                                      \
    XA[2] = xq1[(size_t)vc_ * 8192];                                           \
    XA[3] = xq1[(size_t)vc_ * 8192 + 16];                                      \
    XA[4] = xq2[(size_t)vc_ * 8192];                                           \
    XA[5] = xq2[(size_t)vc_ * 8192 + 16];                                      \
  } while (0)

#define COMPUTEV(PA, XA)                                                       \
  do {                                                                         \
    _Pragma("unroll")                                                          \
    for (int n = 0; n < 2; ++n) {                                              \
      f32x4 tt = {0.f, 0.f, 0.f, 0.f};                                         \
      __builtin_amdgcn_s_setprio(1);                                           \
      tt = __builtin_amdgcn_mfma_f32_16x16x32_bf16(PA[0], b[n][0], tt, 0, 0, 0);\
      tt = __builtin_amdgcn_mfma_f32_16x16x32_bf16(PA[1], b[n][1], tt, 0, 0, 0);\
      tt = __builtin_amdgcn_mfma_f32_16x16x32_bf16(PA[2], b[n][2], tt, 0, 0, 0);\
      tt = __builtin_amdgcn_mfma_f32_16x16x32_bf16(PA[3], b[n][3], tt, 0, 0, 0);\
      __builtin_amdgcn_s_setprio(0);                                           \
      float x0 = bf2f(XA[0 + n]);                                              \
      float x1 = bf2f(XA[2 + n]);                                              \
      float x2 = bf2f(XA[4 + n]);                                              \
      _Pragma("unroll")                                                        \
      for (int r = 0; r < 4; ++r) {                                            \
        acc[n][r][0] += tt[r] * x0;                                            \
        acc[n][r][1] += tt[r] * x1;                                            \
        acc[n][r][2] += tt[r] * x2;                                            \
      }                                                                        \
    }                                                                          \
  } while (0)

__global__ __launch_bounds__(512, 2) void outv_kernel(
    const ushort* __restrict__ xs_bf, const ushort* __restrict__ xvt,
    const ushort* __restrict__ Wt, float* __restrict__ out) {
  __shared__ float red[256][25];     // 25.6KB, epilogue only
  int bid = blockIdx.x;
  int wc = bid & 3, zb = bid >> 2;
  int tid = threadIdx.x;
  int wid = tid >> 6, l = tid & 63;
  int vg = wid & 1, wg = (wid >> 1) & 1, zg = (wid >> 2) & 1;
  int lr = l & 15, lg = l >> 4;
  int zbase = zb * 64 + zg * 32 + lr;   // n-tile adds 16
  int w0 = wc * 32 + wg * 16;
  int vbase = vg * 64;

  // per-wave A stream base: fragment-order tile [wg][kk][l][e]
  const ushort* Ap = Wt + (size_t)wc * SLAB + (size_t)vbase * 4096 + wg * 2048 + l * 8;
  const ushort* xq0 = xvt + ((size_t)(0 * 128 + vbase)) * 8192 + zbase;
  const ushort* xq1 = xvt + ((size_t)(1 * 128 + vbase)) * 8192 + zbase;
  const ushort* xq2 = xvt + ((size_t)(2 * 128 + vbase)) * 8192 + zbase;

  // B-fragments (xs): 2 n-tiles x 4 k-chunks, held all kernel
  bf16x8 b[2][4];
#pragma unroll
  for (int n = 0; n < 2; ++n)
#pragma unroll
    for (int kk = 0; kk < 4; ++kk)
      b[n][kk] = *(const bf16x8*)(xs_bf + (size_t)(zbase + n * 16) * 128 + kk * 32 + lg * 8);

  float acc[2][4][3] = {};
  bf16x8 pa[4], pb[4], pc[4];
  ushort xa[6], xb[6], xc[6];

  LOADV(0, pa, xa);
  LOADV(1, pb, xb);
  LOADV(2, pc, xc);
  __builtin_amdgcn_sched_barrier(0);

  for (int q = 0; q < 21; ++q) {
    COMPUTEV(pa, xa);
    LOADV(3 * q + 3, pa, xa);
    __builtin_amdgcn_sched_barrier(0);
    COMPUTEV(pb, xb);
    LOADV(3 * q + 4, pb, xb);
    __builtin_amdgcn_sched_barrier(0);
    COMPUTEV(pc, xc);
    LOADV(3 * q + 5, pc, xc);
    __builtin_amdgcn_sched_barrier(0);
  }
  COMPUTEV(pa, xa);                  // v = 63 (loaded at q=20 as 3*20+3)

  // vg combine: vg1 -> LDS, vg0 adds + stores
  int rrow = (zg * 2 + wg) * 64 + l;
  if (vg == 1) {
#pragma unroll
    for (int n = 0; n < 2; ++n)
#pragma unroll
      for (int r = 0; r < 4; ++r)
#pragma unroll
        for (int i = 0; i < 3; ++i)
          red[rrow][(n * 4 + r) * 3 + i] = acc[n][r][i];
  }
  __syncthreads();
  if (vg == 0) {
#pragma unroll
    for (int n = 0; n < 2; ++n) {
#pragma unroll
      for (int r = 0; r < 4; ++r) {
        int z = zbase + n * 16;
        int w = w0 + lg * 4 + r;
        float* o = out + (size_t)z * 512 + 128 + 3 * w;
        o[0] = (acc[n][r][0] + red[rrow][(n * 4 + r) * 3 + 0]) * 0.0078125f;
        o[1] = (acc[n][r][1] + red[rrow][(n * 4 + r) * 3 + 1]) * 0.0078125f;
        o[2] = (acc[n][r][2] + red[rrow][(n * 4 + r) * 3 + 2]) * 0.0078125f;
      }
    }
  }
}

// ---------------- launch ----------------------------------------------------
extern "C" void kernel_launch(void* const* d_in, const int* in_sizes, int n_in,
                              void* d_out, int out_size, void* d_ws, size_t ws_size,
                              hipStream_t stream) {
  const float* x    = (const float*)d_in[0];
  const float* w_ss = (const float*)d_in[1];
  const float* w_sv = (const float*)d_in[2];
  const float* w_vv = (const float*)d_in[3];
  float* out = (float*)d_out;

  char* ws = (char*)d_ws;
  ushort* xs_bf = (ushort*)ws;                                  // 2 MB
  ushort* Wt    = (ushort*)(ws + (size_t)2 * 1024 * 1024);      // 4.39 MB used
  ushort* xvt   = (ushort*)(ws + (size_t)6656 * 1024);          // 6 MB @ 6.5MB

  prep_all<<<896, 256, 0, stream>>>(x, w_ss, w_vv, w_sv, xs_bf, xvt, Wt, out);
  outv_kernel<<<512, 512, 0, stream>>>(xs_bf, xvt, Wt, out);
}